// Round 9
// baseline (933.928 us; speedup 1.0000x reference)
//
#include <hip/hip_runtime.h>

#define MAXD 192
#define NCH  16

#define RFL_I(x) __builtin_amdgcn_readfirstlane(x)
#define RFL_F(x) __int_as_float(__builtin_amdgcn_readfirstlane(__float_as_int(x)))
#define RDL(v,k) __int_as_float(__builtin_amdgcn_readlane(__float_as_int(v), (k)))
#define LOADF(base, boff) (*(const float*)((base) + (boff)))

__device__ __forceinline__ float samp(const float* __restrict__ p,
                                      int yb0, int yb1, float wy0, float wy1,
                                      int xb0, int xb1, float mxx0, float mxx1,
                                      float fx) {
    float v00 = p[yb0 + xb0] * mxx0, v01 = p[yb0 + xb1] * mxx1;
    float v10 = p[yb1 + xb0] * mxx0, v11 = p[yb1 + xb1] * mxx1;
    float top = v00 + fx * (v01 - v00);
    float bot = v10 + fx * (v11 - v10);
    return top * wy0 + bot * wy1;
}

// One block per (point n = blockIdx.x, level j = blockIdx.y).
// Waves 0-2: pass-1 (scale 1) disparity chunks [0,64),[64,128),[128,192).
// Wave 3:   pass-0 (scale 4, D=48), level j+8.
// Wave-private LDS strips; only block-wide barrier is the val4 handoff.
// Left 5x5 window: per-lane sample + v_readlane broadcast (no LDS).
// Strip staging: saddr-form loads (scalar row base + per-lane column byte
// offset), x-masks folded into corner weights, 5 rows fully unrolled.
// LESSON (R5/R6/R8): no extra long-lived named values across the channel
// loop — recompute row constants inside the loop (SALU), net-zero VGPR delta.
__global__ __launch_bounds__(256, 8) void pbm_kernel(
    const float* __restrict__ lfeat,   // (16,1,16,H,W)
    const float* __restrict__ rfeat,
    const float* __restrict__ points,  // (1,N,2)
    const int* __restrict__ pW, const int* __restrict__ pH,
    float* __restrict__ out)           // (1,N,192,8)
{
    const int W = RFL_I(*pW), H = RFL_I(*pH);
    const int HW = W * H;
    const int n   = blockIdx.x;
    const int j   = blockIdx.y;        // linear wg = n + N*j, N%8==0 -> same-n same XCD
    const int tid = threadIdx.x;
    const int wv  = tid >> 6;
    const int l   = tid & 63;

    const float pxr = points[2 * n];
    const float pyr = points[2 * n + 1];
    const float pxf = floorf(pxr), pyf = floorf(pyr);
    const float fx  = RFL_F(pxr - pxf);
    const float fy  = RFL_F(pyr - pyf);
    const int   x0i = RFL_I((int)pxf);
    const int   y0i = RFL_I((int)pyf);

    __shared__ float sv[4][5][68];     // per-wave right strip
    __shared__ float val4[48];

    const bool p0     = (wv == 3);
    const int  s_     = RFL_I(p0 ? 4 : 1);
    const int  lvl    = RFL_I(p0 ? j + 8 : j);
    const int  off    = RFL_I(p0 ? 49 : wv * 64 + 65);
    const int  DC     = RFL_I(p0 ? 48 : 64);
    const int  stageN = RFL_I(p0 ? 52 : 64);

    // strip column constants (col == lane): byte offsets + folded x-weights
    const int   cx   = x0i + s_ * (l - off);
    const int   cbB0 = min(max(cx, 0), W - 1) * 4;
    const int   cbB1 = min(max(cx + 1, 0), W - 1) * 4;
    const float ax0  = (((unsigned)cx       < (unsigned)W) ? 1.0f : 0.0f) * (1.0f - fx);
    const float ax1  = (((unsigned)(cx + 1) < (unsigned)W) ? 1.0f : 0.0f) * fx;

    // cleanup taps (pass-1 waves): cols 64+(l&3), row l>>2, lanes<20 (R7 form)
    const int   dyc  = min(l >> 2, 4);
    const int   dcol = 64 + (l & 3);
    const int   dcx  = x0i + s_ * (dcol - off);
    const int   db0  = min(max(dcx, 0), W - 1);
    const int   db1  = min(max(dcx + 1, 0), W - 1);
    const float dmx0 = ((unsigned)dcx       < (unsigned)W) ? 1.0f : 0.0f;
    const float dmx1 = ((unsigned)(dcx + 1) < (unsigned)W) ? 1.0f : 0.0f;
    const int   dyr  = y0i + s_ * (dyc - 2);
    const int   dyb0 = min(max(dyr, 0), H - 1) * W;
    const int   dyb1 = min(max(dyr + 1, 0), H - 1) * W;
    const float dwy0 = ((unsigned)dyr       < (unsigned)H) ? (1.0f - fy) : 0.0f;
    const float dwy1 = ((unsigned)(dyr + 1) < (unsigned)H) ? fy : 0.0f;

    // left window taps: lanes 0..24 meaningful (R7 form)
    const int   lq  = min(l, 24);
    const int   lyy = lq / 5;
    const int   lxx = lq - lyy * 5;
    const int   lx  = x0i + s_ * (lxx - 2);
    const int   ly  = y0i + s_ * (lyy - 2);
    const int   la0 = min(max(lx, 0), W - 1);
    const int   la1 = min(max(lx + 1, 0), W - 1);
    const float lmx0 = ((unsigned)lx       < (unsigned)W) ? 1.0f : 0.0f;
    const float lmx1 = ((unsigned)(lx + 1) < (unsigned)W) ? 1.0f : 0.0f;
    const int   lyb0 = min(max(ly, 0), H - 1) * W;
    const int   lyb1 = min(max(ly + 1, 0), H - 1) * W;
    const float lwy0 = ((unsigned)ly       < (unsigned)H) ? (1.0f - fy) : 0.0f;
    const float lwy1 = ((unsigned)(ly + 1) < (unsigned)H) ? fy : 0.0f;

    const float* Rb = rfeat + (size_t)(lvl * NCH) * HW;
    const float* Lb = lfeat + (size_t)(lvl * NCH) * HW;

    float acc = 0.0f;
#pragma unroll 1
    for (int c = 0; c < NCH; ++c) {
        const float* Rp = Rb + (size_t)c * HW;
        const float* Lp = Lb + (size_t)c * HW;
        const char*  RpC = (const char*)Rp;

        if (l < stageN) {
#pragma unroll
            for (int yy = 0; yy < 5; ++yy) {
                int   yr   = y0i + s_ * (yy - 2);          // uniform -> SALU
                int   rbB0 = min(max(yr, 0), H - 1) * (W * 4);
                int   rbB1 = min(max(yr + 1, 0), H - 1) * (W * 4);
                float wy0  = ((unsigned)yr       < (unsigned)H) ? (1.0f - fy) : 0.0f;
                float wy1  = ((unsigned)(yr + 1) < (unsigned)H) ? fy : 0.0f;
                float v00 = LOADF(RpC + rbB0, cbB0);
                float v01 = LOADF(RpC + rbB0, cbB1);
                float v10 = LOADF(RpC + rbB1, cbB0);
                float v11 = LOADF(RpC + rbB1, cbB1);
                float t = fmaf(ax0, v00, ax1 * v01);
                float b = fmaf(ax0, v10, ax1 * v11);
                sv[wv][yy][l] = fmaf(wy0, t, wy1 * b);
            }
        }
        if (!p0 && l < 20)
            sv[wv][dyc][dcol] = samp(Rp, dyb0, dyb1, dwy0, dwy1, db0, db1, dmx0, dmx1, fx);

        // left window value for this lane's (lyy,lxx); broadcast below
        float lval = samp(Lp, lyb0, lyb1, lwy0, lwy1, la0, la1, lmx0, lmx1, fx);

        // broadcast left window into wave-uniform scalars (no LDS, no array)
        float sk00 = RDL(lval, 0),  sk01 = RDL(lval, 1),  sk02 = RDL(lval, 2);
        float sk03 = RDL(lval, 3),  sk04 = RDL(lval, 4);
        float sk05 = RDL(lval, 5),  sk06 = RDL(lval, 6),  sk07 = RDL(lval, 7);
        float sk08 = RDL(lval, 8),  sk09 = RDL(lval, 9);
        float sk10 = RDL(lval, 10), sk11 = RDL(lval, 11), sk12 = RDL(lval, 12);
        float sk13 = RDL(lval, 13), sk14 = RDL(lval, 14);
        float sk15 = RDL(lval, 15), sk16 = RDL(lval, 16), sk17 = RDL(lval, 17);
        float sk18 = RDL(lval, 18), sk19 = RDL(lval, 19);
        float sk20 = RDL(lval, 20), sk21 = RDL(lval, 21), sk22 = RDL(lval, 22);
        float sk23 = RDL(lval, 23), sk24 = RDL(lval, 24);

        if (l < DC) {
            float a0 = 0.f, a1 = 0.f;
            {
                const float* rp = &sv[wv][0][DC - 1 - l];
                a0 += fabsf(sk00 - rp[0]); a1 += fabsf(sk01 - rp[1]);
                a0 += fabsf(sk02 - rp[2]); a1 += fabsf(sk03 - rp[3]);
                a0 += fabsf(sk04 - rp[4]);
            }
            {
                const float* rp = &sv[wv][1][DC - 1 - l];
                a0 += fabsf(sk05 - rp[0]); a1 += fabsf(sk06 - rp[1]);
                a0 += fabsf(sk07 - rp[2]); a1 += fabsf(sk08 - rp[3]);
                a0 += fabsf(sk09 - rp[4]);
            }
            {
                const float* rp = &sv[wv][2][DC - 1 - l];
                a0 += fabsf(sk10 - rp[0]); a1 += fabsf(sk11 - rp[1]);
                a0 += fabsf(sk12 - rp[2]); a1 += fabsf(sk13 - rp[3]);
                a0 += fabsf(sk14 - rp[4]);
            }
            {
                const float* rp = &sv[wv][3][DC - 1 - l];
                a0 += fabsf(sk15 - rp[0]); a1 += fabsf(sk16 - rp[1]);
                a0 += fabsf(sk17 - rp[2]); a1 += fabsf(sk18 - rp[3]);
                a0 += fabsf(sk19 - rp[4]);
            }
            {
                const float* rp = &sv[wv][4][DC - 1 - l];
                a0 += fabsf(sk20 - rp[0]); a1 += fabsf(sk21 - rp[1]);
                a0 += fabsf(sk22 - rp[2]); a1 += fabsf(sk23 - rp[3]);
                a0 += fabsf(sk24 - rp[4]);
            }
            acc += a0 + a1;
        }
    }

    if (p0 && l < 48)
        val4[l] = 1.0f - expf(-acc * (1.0f / 400.0f));

    __syncthreads();                     // the ONLY block-wide barrier

    if (tid < MAXD) {                    // waves 0-2: d == tid
        float v1  = 1.0f - expf(-acc * (1.0f / 400.0f));
        float pos = (float)tid * (47.0f / 191.0f);
        float i0f = floorf(pos);
        int   i0  = (int)i0f;
        float w   = pos - i0f;
        int   i1  = min(i0 + 1, 47);
        float up  = val4[i0] + w * (val4[i1] - val4[i0]);
        out[((size_t)n * MAXD + tid) * 8 + j] = v1 + up;
    }
}

extern "C" void kernel_launch(void* const* d_in, const int* in_sizes, int n_in,
                              void* d_out, int out_size, void* d_ws, size_t ws_size,
                              hipStream_t stream) {
    const float* lf  = (const float*)d_in[0];
    const float* rf  = (const float*)d_in[1];
    const float* pts = (const float*)d_in[2];
    const int*   pW  = (const int*)d_in[3];
    const int*   pH  = (const int*)d_in[4];
    float* out = (float*)d_out;

    const int N = in_sizes[2] / 2;       // (B=1, N, 2)
    pbm_kernel<<<dim3(N, 8), 256, 0, stream>>>(lf, rf, pts, pW, pH, out);
}

// Round 10
// 219.345 us; speedup vs baseline: 4.2578x; 4.2578x over previous
//
#include <hip/hip_runtime.h>

#define MAXD 192
#define NCH  16

#define RFL_I(x) __builtin_amdgcn_readfirstlane(x)
#define RFL_F(x) __int_as_float(__builtin_amdgcn_readfirstlane(__float_as_int(x)))
#define RDL(v,k) __int_as_float(__builtin_amdgcn_readlane(__float_as_int(v), (k)))

struct F2 { float x, y; };   // align 4: dword-aligned pair load (HW allows)
#define LOADF2(base, boff) (*(const F2*)((base) + (boff)))

// One block per (point n = blockIdx.x, level j = blockIdx.y).
// Waves 0-2: pass-1 (scale 1) disparity chunks [0,64),[64,128),[128,192).
// Wave 3:   pass-0 (scale 4, D=48), level j+8.
// Wave-private LDS strips; only block-wide barrier is the val4 handoff.
// Left 5x5 window: per-lane sample + v_readlane broadcast (no LDS).
// Bilinear x-corners are ADJACENT pixels -> one dwordx2 pair-load per row
// pair; clamp-select + x-validity masks fold into two loop-invariant
// per-lane weights (w0,w1): row = w0*pair.x + w1*pair.y.
// LESSON (R5/R6/R8/R9): keep R7's loop shape — unroll-1 row loop, row
// constants recomputed inside (SALU), no extra long-lived named values.
__global__ __launch_bounds__(256, 8) void pbm_kernel(
    const float* __restrict__ lfeat,   // (16,1,16,H,W)
    const float* __restrict__ rfeat,
    const float* __restrict__ points,  // (1,N,2)
    const int* __restrict__ pW, const int* __restrict__ pH,
    float* __restrict__ out)           // (1,N,192,8)
{
    const int W = RFL_I(*pW), H = RFL_I(*pH);
    const int HW = W * H;
    const int n   = blockIdx.x;
    const int j   = blockIdx.y;        // linear wg = n + N*j, N%8==0 -> same-n same XCD
    const int tid = threadIdx.x;
    const int wv  = tid >> 6;
    const int l   = tid & 63;

    const float pxr = points[2 * n];
    const float pyr = points[2 * n + 1];
    const float pxf = floorf(pxr), pyf = floorf(pyr);
    const float fx  = RFL_F(pxr - pxf);
    const float fy  = RFL_F(pyr - pyf);
    const int   x0i = RFL_I((int)pxf);
    const int   y0i = RFL_I((int)pyf);

    __shared__ float sv[4][5][68];     // per-wave right strip
    __shared__ float val4[48];

    const bool isP0   = (wv == 3);
    const int  s_     = RFL_I(isP0 ? 4 : 1);
    const int  lvl    = RFL_I(isP0 ? j + 8 : j);
    const int  off    = RFL_I(isP0 ? 49 : wv * 64 + 65);
    const int  DC     = RFL_I(isP0 ? 48 : 64);
    const int  stageN = RFL_I(isP0 ? 52 : 64);

    // ---- strip column constants (col == lane): pair offset + folded weights
    const int   cx    = x0i + s_ * (l - off);
    const int   pairB = min(max(cx, 0), W - 2) * 4;
    {   // scope temporaries so they don't live across the loop
    }
    const float ax0   = (((unsigned)cx       < (unsigned)W) ? 1.0f : 0.0f) * (1.0f - fx);
    const float ax1   = (((unsigned)(cx + 1) < (unsigned)W) ? 1.0f : 0.0f) * fx;
    const float w0    = ((cx >= W - 1) ? 0.f : ax0) + ((cx >= 0) ? 0.f : ax1);
    const float w1    = ((cx >= W - 1) ? ax0 : 0.f) + ((cx >= 0) ? ax1 : 0.f);

    // ---- cleanup taps (pass-1 waves, lanes<20): col 64+(l&3), row l>>2 ----
    const int   dyc  = min(l >> 2, 4);
    const int   dcol = 64 + (l & 3);
    const int   dcx  = x0i + s_ * (dcol - off);
    const float dax0 = (((unsigned)dcx       < (unsigned)W) ? 1.0f : 0.0f) * (1.0f - fx);
    const float dax1 = (((unsigned)(dcx + 1) < (unsigned)W) ? 1.0f : 0.0f) * fx;
    const float w0d  = ((dcx >= W - 1) ? 0.f : dax0) + ((dcx >= 0) ? 0.f : dax1);
    const float w1d  = ((dcx >= W - 1) ? dax0 : 0.f) + ((dcx >= 0) ? dax1 : 0.f);
    const int   dyr  = y0i + s_ * (dyc - 2);
    const int   voA  = min(max(dyr, 0), H - 1) * (W * 4) + min(max(dcx, 0), W - 2) * 4;
    const int   voB  = min(max(dyr + 1, 0), H - 1) * (W * 4) + min(max(dcx, 0), W - 2) * 4;
    const float dwy0 = ((unsigned)dyr       < (unsigned)H) ? (1.0f - fy) : 0.0f;
    const float dwy1 = ((unsigned)(dyr + 1) < (unsigned)H) ? fy : 0.0f;

    // ---- left window taps (lanes 0..24 meaningful) ----
    const int   lq   = min(l, 24);
    const int   lyy  = lq / 5;
    const int   lxx  = lq - lyy * 5;
    const int   lx   = x0i + s_ * (lxx - 2);
    const int   ly   = y0i + s_ * (lyy - 2);
    const float lax0 = (((unsigned)lx       < (unsigned)W) ? 1.0f : 0.0f) * (1.0f - fx);
    const float lax1 = (((unsigned)(lx + 1) < (unsigned)W) ? 1.0f : 0.0f) * fx;
    const float w0l  = ((lx >= W - 1) ? 0.f : lax0) + ((lx >= 0) ? 0.f : lax1);
    const float w1l  = ((lx >= W - 1) ? lax0 : 0.f) + ((lx >= 0) ? lax1 : 0.f);
    const int   loA  = min(max(ly, 0), H - 1) * (W * 4) + min(max(lx, 0), W - 2) * 4;
    const int   loB  = min(max(ly + 1, 0), H - 1) * (W * 4) + min(max(lx, 0), W - 2) * 4;
    const float lwy0 = ((unsigned)ly       < (unsigned)H) ? (1.0f - fy) : 0.0f;
    const float lwy1 = ((unsigned)(ly + 1) < (unsigned)H) ? fy : 0.0f;

    const char* RbC = (const char*)(rfeat + (size_t)(lvl * NCH) * HW);
    const char* LbC = (const char*)(lfeat + (size_t)(lvl * NCH) * HW);

    float acc = 0.0f;
#pragma unroll 1
    for (int c = 0; c < NCH; ++c) {
        const char* RpC = RbC + (size_t)c * HW * 4;
        const char* LpC = LbC + (size_t)c * HW * 4;

        if (l < stageN) {
#pragma unroll 1
            for (int yy = 0; yy < 5; ++yy) {
                int   yr   = y0i + s_ * (yy - 2);          // uniform -> SALU
                int   rbB0 = min(max(yr, 0), H - 1) * (W * 4);
                int   rbB1 = min(max(yr + 1, 0), H - 1) * (W * 4);
                float wy0  = ((unsigned)yr       < (unsigned)H) ? (1.0f - fy) : 0.0f;
                float wy1  = ((unsigned)(yr + 1) < (unsigned)H) ? fy : 0.0f;
                F2 pa = LOADF2(RpC + rbB0, pairB);
                F2 pb = LOADF2(RpC + rbB1, pairB);
                float h0 = fmaf(w0, pa.x, w1 * pa.y);
                float h1 = fmaf(w0, pb.x, w1 * pb.y);
                sv[wv][yy][l] = fmaf(wy0, h0, wy1 * h1);
            }
        }
        if (!isP0 && l < 20) {
            F2 pa = LOADF2(RpC, voA);
            F2 pb = LOADF2(RpC, voB);
            float h0 = fmaf(w0d, pa.x, w1d * pa.y);
            float h1 = fmaf(w0d, pb.x, w1d * pb.y);
            sv[wv][dyc][dcol] = fmaf(dwy0, h0, dwy1 * h1);
        }
        float lval;
        {
            F2 pa = LOADF2(LpC, loA);
            F2 pb = LOADF2(LpC, loB);
            float h0 = fmaf(w0l, pa.x, w1l * pa.y);
            float h1 = fmaf(w0l, pb.x, w1l * pb.y);
            lval = fmaf(lwy0, h0, lwy1 * h1);
        }

        // broadcast left window into wave-uniform scalars (no LDS, no array)
        float sk00 = RDL(lval, 0),  sk01 = RDL(lval, 1),  sk02 = RDL(lval, 2);
        float sk03 = RDL(lval, 3),  sk04 = RDL(lval, 4);
        float sk05 = RDL(lval, 5),  sk06 = RDL(lval, 6),  sk07 = RDL(lval, 7);
        float sk08 = RDL(lval, 8),  sk09 = RDL(lval, 9);
        float sk10 = RDL(lval, 10), sk11 = RDL(lval, 11), sk12 = RDL(lval, 12);
        float sk13 = RDL(lval, 13), sk14 = RDL(lval, 14);
        float sk15 = RDL(lval, 15), sk16 = RDL(lval, 16), sk17 = RDL(lval, 17);
        float sk18 = RDL(lval, 18), sk19 = RDL(lval, 19);
        float sk20 = RDL(lval, 20), sk21 = RDL(lval, 21), sk22 = RDL(lval, 22);
        float sk23 = RDL(lval, 23), sk24 = RDL(lval, 24);

        if (l < DC) {
            float a0 = 0.f, a1 = 0.f;
            {
                const float* rp = &sv[wv][0][DC - 1 - l];
                a0 += fabsf(sk00 - rp[0]); a1 += fabsf(sk01 - rp[1]);
                a0 += fabsf(sk02 - rp[2]); a1 += fabsf(sk03 - rp[3]);
                a0 += fabsf(sk04 - rp[4]);
            }
            {
                const float* rp = &sv[wv][1][DC - 1 - l];
                a0 += fabsf(sk05 - rp[0]); a1 += fabsf(sk06 - rp[1]);
                a0 += fabsf(sk07 - rp[2]); a1 += fabsf(sk08 - rp[3]);
                a0 += fabsf(sk09 - rp[4]);
            }
            {
                const float* rp = &sv[wv][2][DC - 1 - l];
                a0 += fabsf(sk10 - rp[0]); a1 += fabsf(sk11 - rp[1]);
                a0 += fabsf(sk12 - rp[2]); a1 += fabsf(sk13 - rp[3]);
                a0 += fabsf(sk14 - rp[4]);
            }
            {
                const float* rp = &sv[wv][3][DC - 1 - l];
                a0 += fabsf(sk15 - rp[0]); a1 += fabsf(sk16 - rp[1]);
                a0 += fabsf(sk17 - rp[2]); a1 += fabsf(sk18 - rp[3]);
                a0 += fabsf(sk19 - rp[4]);
            }
            {
                const float* rp = &sv[wv][4][DC - 1 - l];
                a0 += fabsf(sk20 - rp[0]); a1 += fabsf(sk21 - rp[1]);
                a0 += fabsf(sk22 - rp[2]); a1 += fabsf(sk23 - rp[3]);
                a0 += fabsf(sk24 - rp[4]);
            }
            acc += a0 + a1;
        }
    }

    if (isP0 && l < 48)
        val4[l] = 1.0f - expf(-acc * (1.0f / 400.0f));

    __syncthreads();                     // the ONLY block-wide barrier

    if (tid < MAXD) {                    // waves 0-2: d == tid
        float v1  = 1.0f - expf(-acc * (1.0f / 400.0f));
        float pos = (float)tid * (47.0f / 191.0f);
        float i0f = floorf(pos);
        int   i0  = (int)i0f;
        float w   = pos - i0f;
        int   i1  = min(i0 + 1, 47);
        float up  = val4[i0] + w * (val4[i1] - val4[i0]);
        out[((size_t)n * MAXD + tid) * 8 + j] = v1 + up;
    }
}

extern "C" void kernel_launch(void* const* d_in, const int* in_sizes, int n_in,
                              void* d_out, int out_size, void* d_ws, size_t ws_size,
                              hipStream_t stream) {
    const float* lf  = (const float*)d_in[0];
    const float* rf  = (const float*)d_in[1];
    const float* pts = (const float*)d_in[2];
    const int*   pW  = (const int*)d_in[3];
    const int*   pH  = (const int*)d_in[4];
    float* out = (float*)d_out;

    const int N = in_sizes[2] / 2;       // (B=1, N, 2)
    pbm_kernel<<<dim3(N, 8), 256, 0, stream>>>(lf, rf, pts, pW, pH, out);
}

// Round 11
// 215.057 us; speedup vs baseline: 4.3427x; 1.0199x over previous
//
#include <hip/hip_runtime.h>

#define MAXD 192
#define NCH  16

#define RFL_I(x) __builtin_amdgcn_readfirstlane(x)
#define RFL_F(x) __int_as_float(__builtin_amdgcn_readfirstlane(__float_as_int(x)))
#define RDL(v,k) __int_as_float(__builtin_amdgcn_readlane(__float_as_int(v), (k)))

struct F2 { float x, y; };   // align 4: dword-aligned global pair load
#define LOADF2(base, boff) (*(const F2*)((base) + (boff)))

// One block per (point n = blockIdx.x, level j = blockIdx.y).
// Waves 0-2: pass-1 (scale 1) disparity chunks [0,64),[64,128),[128,192).
// Wave 3:   pass-0 (scale 4, D=48), level j+8.
// Wave-private LDS strips; only block-wide barrier is the val4 handoff.
// TWO channels per iteration, strip stored as float2 in LDS:
//   ds_write_b64 stages both channels; ds_read_b64 taps both channels
//   -> DS-pipe instructions per channel halved (the R10 bottleneck).
// Bilinear x-corners are adjacent pixels -> dwordx2 pair-load; clamp-select
// + x-validity fold into loop-invariant weights (w0,w1) [verified R10].
// LESSON (R5/R6/R8/R9): keep unroll-1 loops, recompute row constants inside
// (SALU), no extra long-lived named values across the channel loop.
__global__ __launch_bounds__(256, 8) void pbm_kernel(
    const float* __restrict__ lfeat,   // (16,1,16,H,W)
    const float* __restrict__ rfeat,
    const float* __restrict__ points,  // (1,N,2)
    const int* __restrict__ pW, const int* __restrict__ pH,
    float* __restrict__ out)           // (1,N,192,8)
{
    const int W = RFL_I(*pW), H = RFL_I(*pH);
    const int HW = W * H;
    const int n   = blockIdx.x;
    const int j   = blockIdx.y;        // linear wg = n + N*j, N%8==0 -> same-n same XCD
    const int tid = threadIdx.x;
    const int wv  = tid >> 6;
    const int l   = tid & 63;

    const float pxr = points[2 * n];
    const float pyr = points[2 * n + 1];
    const float pxf = floorf(pxr), pyf = floorf(pyr);
    const float fx  = RFL_F(pxr - pxf);
    const float fy  = RFL_F(pyr - pyf);
    const int   x0i = RFL_I((int)pxf);
    const int   y0i = RFL_I((int)pyf);

    __shared__ float2 sv2[4][5][68];   // per-wave right strip, 2 channels packed
    __shared__ float  val4[48];

    const bool isP0   = (wv == 3);
    const int  s_     = RFL_I(isP0 ? 4 : 1);
    const int  lvl    = RFL_I(isP0 ? j + 8 : j);
    const int  off    = RFL_I(isP0 ? 49 : wv * 64 + 65);
    const int  DC     = RFL_I(isP0 ? 48 : 64);
    const int  stageN = RFL_I(isP0 ? 52 : 64);

    // ---- strip column constants (col == lane): pair offset + folded weights
    const int   cx    = x0i + s_ * (l - off);
    const int   pairB = min(max(cx, 0), W - 2) * 4;
    const float ax0   = (((unsigned)cx       < (unsigned)W) ? 1.0f : 0.0f) * (1.0f - fx);
    const float ax1   = (((unsigned)(cx + 1) < (unsigned)W) ? 1.0f : 0.0f) * fx;
    const float w0    = ((cx >= W - 1) ? 0.f : ax0) + ((cx >= 0) ? 0.f : ax1);
    const float w1    = ((cx >= W - 1) ? ax0 : 0.f) + ((cx >= 0) ? ax1 : 0.f);

    // ---- cleanup taps (pass-1 waves, lanes<20): col 64+(l&3), row l>>2 ----
    const int   dyc  = min(l >> 2, 4);
    const int   dcol = 64 + (l & 3);
    const int   dcx  = x0i + s_ * (dcol - off);
    const float dax0 = (((unsigned)dcx       < (unsigned)W) ? 1.0f : 0.0f) * (1.0f - fx);
    const float dax1 = (((unsigned)(dcx + 1) < (unsigned)W) ? 1.0f : 0.0f) * fx;
    const float w0d  = ((dcx >= W - 1) ? 0.f : dax0) + ((dcx >= 0) ? 0.f : dax1);
    const float w1d  = ((dcx >= W - 1) ? dax0 : 0.f) + ((dcx >= 0) ? dax1 : 0.f);
    const int   dyr  = y0i + s_ * (dyc - 2);
    const int   voA  = min(max(dyr, 0), H - 1) * (W * 4) + min(max(dcx, 0), W - 2) * 4;
    const int   voB  = min(max(dyr + 1, 0), H - 1) * (W * 4) + min(max(dcx, 0), W - 2) * 4;
    const float dwy0 = ((unsigned)dyr       < (unsigned)H) ? (1.0f - fy) : 0.0f;
    const float dwy1 = ((unsigned)(dyr + 1) < (unsigned)H) ? fy : 0.0f;

    // ---- left window taps (lanes 0..24 meaningful) ----
    const int   lq   = min(l, 24);
    const int   lyy  = lq / 5;
    const int   lxx  = lq - lyy * 5;
    const int   lx   = x0i + s_ * (lxx - 2);
    const int   ly   = y0i + s_ * (lyy - 2);
    const float lax0 = (((unsigned)lx       < (unsigned)W) ? 1.0f : 0.0f) * (1.0f - fx);
    const float lax1 = (((unsigned)(lx + 1) < (unsigned)W) ? 1.0f : 0.0f) * fx;
    const float w0l  = ((lx >= W - 1) ? 0.f : lax0) + ((lx >= 0) ? 0.f : lax1);
    const float w1l  = ((lx >= W - 1) ? lax0 : 0.f) + ((lx >= 0) ? lax1 : 0.f);
    const int   loA  = min(max(ly, 0), H - 1) * (W * 4) + min(max(lx, 0), W - 2) * 4;
    const int   loB  = min(max(ly + 1, 0), H - 1) * (W * 4) + min(max(lx, 0), W - 2) * 4;
    const float lwy0 = ((unsigned)ly       < (unsigned)H) ? (1.0f - fy) : 0.0f;
    const float lwy1 = ((unsigned)(ly + 1) < (unsigned)H) ? fy : 0.0f;

    const char* RbC = (const char*)(rfeat + (size_t)(lvl * NCH) * HW);
    const char* LbC = (const char*)(lfeat + (size_t)(lvl * NCH) * HW);

    float acc = 0.0f;
#pragma unroll 1
    for (int c = 0; c < NCH; c += 2) {
        const char* RpC0 = RbC + (size_t)c * HW * 4;
        const char* RpC1 = RpC0 + (size_t)HW * 4;
        const char* LpC0 = LbC + (size_t)c * HW * 4;
        const char* LpC1 = LpC0 + (size_t)HW * 4;

        if (l < stageN) {
#pragma unroll 1
            for (int yy = 0; yy < 5; ++yy) {
                int   yr   = y0i + s_ * (yy - 2);          // uniform -> SALU
                int   rbB0 = min(max(yr, 0), H - 1) * (W * 4);
                int   rbB1 = min(max(yr + 1, 0), H - 1) * (W * 4);
                float wy0  = ((unsigned)yr       < (unsigned)H) ? (1.0f - fy) : 0.0f;
                float wy1  = ((unsigned)(yr + 1) < (unsigned)H) ? fy : 0.0f;
                F2 a0 = LOADF2(RpC0 + rbB0, pairB);
                F2 b0 = LOADF2(RpC0 + rbB1, pairB);
                F2 a1 = LOADF2(RpC1 + rbB0, pairB);
                F2 b1 = LOADF2(RpC1 + rbB1, pairB);
                float h00 = fmaf(w0, a0.x, w1 * a0.y);
                float h01 = fmaf(w0, b0.x, w1 * b0.y);
                float h10 = fmaf(w0, a1.x, w1 * a1.y);
                float h11 = fmaf(w0, b1.x, w1 * b1.y);
                float2 r;
                r.x = fmaf(wy0, h00, wy1 * h01);
                r.y = fmaf(wy0, h10, wy1 * h11);
                sv2[wv][yy][l] = r;                        // ds_write_b64
            }
        }
        if (!isP0 && l < 20) {
            F2 pa0 = LOADF2(RpC0, voA);
            F2 pb0 = LOADF2(RpC0, voB);
            F2 pa1 = LOADF2(RpC1, voA);
            F2 pb1 = LOADF2(RpC1, voB);
            float h00 = fmaf(w0d, pa0.x, w1d * pa0.y);
            float h01 = fmaf(w0d, pb0.x, w1d * pb0.y);
            float h10 = fmaf(w0d, pa1.x, w1d * pa1.y);
            float h11 = fmaf(w0d, pb1.x, w1d * pb1.y);
            float2 r;
            r.x = fmaf(dwy0, h00, dwy1 * h01);
            r.y = fmaf(dwy0, h10, dwy1 * h11);
            sv2[wv][dyc][dcol] = r;                        // ds_write_b64
        }
        float lval0, lval1;
        {
            F2 pa0 = LOADF2(LpC0, loA);
            F2 pb0 = LOADF2(LpC0, loB);
            F2 pa1 = LOADF2(LpC1, loA);
            F2 pb1 = LOADF2(LpC1, loB);
            float h00 = fmaf(w0l, pa0.x, w1l * pa0.y);
            float h01 = fmaf(w0l, pb0.x, w1l * pb0.y);
            float h10 = fmaf(w0l, pa1.x, w1l * pa1.y);
            float h11 = fmaf(w0l, pb1.x, w1l * pb1.y);
            lval0 = fmaf(lwy0, h00, lwy1 * h01);
            lval1 = fmaf(lwy0, h10, lwy1 * h11);
        }

        if (l < DC) {
            float a0 = 0.f, a1 = 0.f;
#define TAPROW(YY) {                                                        \
            const float2* rp = &sv2[wv][YY][DC - 1 - l];                    \
            float2 q0 = rp[0], q1 = rp[1], q2 = rp[2], q3 = rp[3], q4 = rp[4];\
            float sx0 = RDL(lval0, (YY)*5+0), sy0 = RDL(lval1, (YY)*5+0);   \
            float sx1 = RDL(lval0, (YY)*5+1), sy1 = RDL(lval1, (YY)*5+1);   \
            float sx2 = RDL(lval0, (YY)*5+2), sy2 = RDL(lval1, (YY)*5+2);   \
            float sx3 = RDL(lval0, (YY)*5+3), sy3 = RDL(lval1, (YY)*5+3);   \
            float sx4 = RDL(lval0, (YY)*5+4), sy4 = RDL(lval1, (YY)*5+4);   \
            a0 += fabsf(sx0 - q0.x); a1 += fabsf(sy0 - q0.y);               \
            a0 += fabsf(sx1 - q1.x); a1 += fabsf(sy1 - q1.y);               \
            a0 += fabsf(sx2 - q2.x); a1 += fabsf(sy2 - q2.y);               \
            a0 += fabsf(sx3 - q3.x); a1 += fabsf(sy3 - q3.y);               \
            a0 += fabsf(sx4 - q4.x); a1 += fabsf(sy4 - q4.y); }
            TAPROW(0)
            TAPROW(1)
            TAPROW(2)
            TAPROW(3)
            TAPROW(4)
#undef TAPROW
            acc += a0 + a1;
        }
    }

    if (isP0 && l < 48)
        val4[l] = 1.0f - expf(-acc * (1.0f / 400.0f));

    __syncthreads();                     // the ONLY block-wide barrier

    if (tid < MAXD) {                    // waves 0-2: d == tid
        float v1  = 1.0f - expf(-acc * (1.0f / 400.0f));
        float pos = (float)tid * (47.0f / 191.0f);
        float i0f = floorf(pos);
        int   i0  = (int)i0f;
        float w   = pos - i0f;
        int   i1  = min(i0 + 1, 47);
        float up  = val4[i0] + w * (val4[i1] - val4[i0]);
        out[((size_t)n * MAXD + tid) * 8 + j] = v1 + up;
    }
}

extern "C" void kernel_launch(void* const* d_in, const int* in_sizes, int n_in,
                              void* d_out, int out_size, void* d_ws, size_t ws_size,
                              hipStream_t stream) {
    const float* lf  = (const float*)d_in[0];
    const float* rf  = (const float*)d_in[1];
    const float* pts = (const float*)d_in[2];
    const int*   pW  = (const int*)d_in[3];
    const int*   pH  = (const int*)d_in[4];
    float* out = (float*)d_out;

    const int N = in_sizes[2] / 2;       // (B=1, N, 2)
    pbm_kernel<<<dim3(N, 8), 256, 0, stream>>>(lf, rf, pts, pW, pH, out);
}

// Round 12
// 209.073 us; speedup vs baseline: 4.4670x; 1.0286x over previous
//
#include <hip/hip_runtime.h>
#include <hip/hip_fp16.h>

#define MAXD 192
#define NCH  16

#define RFL_I(x) __builtin_amdgcn_readfirstlane(x)
#define RFL_F(x) __int_as_float(__builtin_amdgcn_readfirstlane(__float_as_int(x)))
#define RDLU(v,k) ((unsigned)__builtin_amdgcn_readlane((int)(v), (k)))
#define H2(u) __builtin_bit_cast(__half2, (unsigned)(u))
#define U32(h) __builtin_bit_cast(unsigned, (h))

struct F2 { float x, y; };   // align 4: dword-aligned global pair load
#define LOADF2(base, boff) (*(const F2*)((base) + (boff)))

// One block per (point n = blockIdx.x, level j = blockIdx.y).
// Waves 0-2: pass-1 (scale 1) disparity chunks [0,64),[64,128),[128,192).
// Wave 3:   pass-0 (scale 4, D=48), level j+8.
// Wave-private LDS strips; only block-wide barrier is the val4 handoff.
// TWO channels per iteration, strip packed as half2 in LDS:
//   taps use packed-f16 VALU (__hsub2/__habs2/__hadd2) -> 3 pk-ops per
//   2 channels per tap (vs 4 f32 ops), readlane broadcast halved (packed
//   u32), tap DS reads are b32. Per-iter accumulation in two half2 chains
//   (partials <= ~15), converted to f32 each iteration -> added error
//   ~0.003, well under threshold.
// Bilinear x-corners are adjacent pixels -> dwordx2 pair-load; clamp-select
// + x-validity fold into loop-invariant weights (w0,w1) [verified R10].
// LESSON (R5/R6/R8/R9): keep unroll-1 loops, recompute row constants inside
// (SALU), no extra long-lived named values across the channel loop.
__global__ __launch_bounds__(256, 8) void pbm_kernel(
    const float* __restrict__ lfeat,   // (16,1,16,H,W)
    const float* __restrict__ rfeat,
    const float* __restrict__ points,  // (1,N,2)
    const int* __restrict__ pW, const int* __restrict__ pH,
    float* __restrict__ out)           // (1,N,192,8)
{
    const int W = RFL_I(*pW), H = RFL_I(*pH);
    const int HW = W * H;
    const int n   = blockIdx.x;
    const int j   = blockIdx.y;        // linear wg = n + N*j, N%8==0 -> same-n same XCD
    const int tid = threadIdx.x;
    const int wv  = tid >> 6;
    const int l   = tid & 63;

    const float pxr = points[2 * n];
    const float pyr = points[2 * n + 1];
    const float pxf = floorf(pxr), pyf = floorf(pyr);
    const float fx  = RFL_F(pxr - pxf);
    const float fy  = RFL_F(pyr - pyf);
    const int   x0i = RFL_I((int)pxf);
    const int   y0i = RFL_I((int)pyf);

    __shared__ unsigned svh[4][5][68]; // per-wave right strip, half2 (2 ch packed)
    __shared__ float    val4[48];

    const bool isP0   = (wv == 3);
    const int  s_     = RFL_I(isP0 ? 4 : 1);
    const int  lvl    = RFL_I(isP0 ? j + 8 : j);
    const int  off    = RFL_I(isP0 ? 49 : wv * 64 + 65);
    const int  DC     = RFL_I(isP0 ? 48 : 64);
    const int  stageN = RFL_I(isP0 ? 52 : 64);

    // ---- strip column constants (col == lane): pair offset + folded weights
    const int   cx    = x0i + s_ * (l - off);
    const int   pairB = min(max(cx, 0), W - 2) * 4;
    const float ax0   = (((unsigned)cx       < (unsigned)W) ? 1.0f : 0.0f) * (1.0f - fx);
    const float ax1   = (((unsigned)(cx + 1) < (unsigned)W) ? 1.0f : 0.0f) * fx;
    const float w0    = ((cx >= W - 1) ? 0.f : ax0) + ((cx >= 0) ? 0.f : ax1);
    const float w1    = ((cx >= W - 1) ? ax0 : 0.f) + ((cx >= 0) ? ax1 : 0.f);

    // ---- cleanup taps (pass-1 waves, lanes<20): col 64+(l&3), row l>>2 ----
    const int   dyc  = min(l >> 2, 4);
    const int   dcol = 64 + (l & 3);
    const int   dcx  = x0i + s_ * (dcol - off);
    const float dax0 = (((unsigned)dcx       < (unsigned)W) ? 1.0f : 0.0f) * (1.0f - fx);
    const float dax1 = (((unsigned)(dcx + 1) < (unsigned)W) ? 1.0f : 0.0f) * fx;
    const float w0d  = ((dcx >= W - 1) ? 0.f : dax0) + ((dcx >= 0) ? 0.f : dax1);
    const float w1d  = ((dcx >= W - 1) ? dax0 : 0.f) + ((dcx >= 0) ? dax1 : 0.f);
    const int   dyr  = y0i + s_ * (dyc - 2);
    const int   voA  = min(max(dyr, 0), H - 1) * (W * 4) + min(max(dcx, 0), W - 2) * 4;
    const int   voB  = min(max(dyr + 1, 0), H - 1) * (W * 4) + min(max(dcx, 0), W - 2) * 4;
    const float dwy0 = ((unsigned)dyr       < (unsigned)H) ? (1.0f - fy) : 0.0f;
    const float dwy1 = ((unsigned)(dyr + 1) < (unsigned)H) ? fy : 0.0f;

    // ---- left window taps (lanes 0..24 meaningful) ----
    const int   lq   = min(l, 24);
    const int   lyy  = lq / 5;
    const int   lxx  = lq - lyy * 5;
    const int   lx   = x0i + s_ * (lxx - 2);
    const int   ly   = y0i + s_ * (lyy - 2);
    const float lax0 = (((unsigned)lx       < (unsigned)W) ? 1.0f : 0.0f) * (1.0f - fx);
    const float lax1 = (((unsigned)(lx + 1) < (unsigned)W) ? 1.0f : 0.0f) * fx;
    const float w0l  = ((lx >= W - 1) ? 0.f : lax0) + ((lx >= 0) ? 0.f : lax1);
    const float w1l  = ((lx >= W - 1) ? lax0 : 0.f) + ((lx >= 0) ? lax1 : 0.f);
    const int   loA  = min(max(ly, 0), H - 1) * (W * 4) + min(max(lx, 0), W - 2) * 4;
    const int   loB  = min(max(ly + 1, 0), H - 1) * (W * 4) + min(max(lx, 0), W - 2) * 4;
    const float lwy0 = ((unsigned)ly       < (unsigned)H) ? (1.0f - fy) : 0.0f;
    const float lwy1 = ((unsigned)(ly + 1) < (unsigned)H) ? fy : 0.0f;

    const char* RbC = (const char*)(rfeat + (size_t)(lvl * NCH) * HW);
    const char* LbC = (const char*)(lfeat + (size_t)(lvl * NCH) * HW);

    float acc = 0.0f;
#pragma unroll 1
    for (int c = 0; c < NCH; c += 2) {
        const char* RpC0 = RbC + (size_t)c * HW * 4;
        const char* RpC1 = RpC0 + (size_t)HW * 4;
        const char* LpC0 = LbC + (size_t)c * HW * 4;
        const char* LpC1 = LpC0 + (size_t)HW * 4;

        if (l < stageN) {
#pragma unroll 1
            for (int yy = 0; yy < 5; ++yy) {
                int   yr   = y0i + s_ * (yy - 2);          // uniform -> SALU
                int   rbB0 = min(max(yr, 0), H - 1) * (W * 4);
                int   rbB1 = min(max(yr + 1, 0), H - 1) * (W * 4);
                float wy0  = ((unsigned)yr       < (unsigned)H) ? (1.0f - fy) : 0.0f;
                float wy1  = ((unsigned)(yr + 1) < (unsigned)H) ? fy : 0.0f;
                F2 a0 = LOADF2(RpC0 + rbB0, pairB);
                F2 b0 = LOADF2(RpC0 + rbB1, pairB);
                F2 a1 = LOADF2(RpC1 + rbB0, pairB);
                F2 b1 = LOADF2(RpC1 + rbB1, pairB);
                float h00 = fmaf(w0, a0.x, w1 * a0.y);
                float h01 = fmaf(w0, b0.x, w1 * b0.y);
                float h10 = fmaf(w0, a1.x, w1 * a1.y);
                float h11 = fmaf(w0, b1.x, w1 * b1.y);
                float rx = fmaf(wy0, h00, wy1 * h01);
                float ry = fmaf(wy0, h10, wy1 * h11);
                svh[wv][yy][l] = U32(__floats2half2_rn(rx, ry));
            }
        }
        if (!isP0 && l < 20) {
            F2 pa0 = LOADF2(RpC0, voA);
            F2 pb0 = LOADF2(RpC0, voB);
            F2 pa1 = LOADF2(RpC1, voA);
            F2 pb1 = LOADF2(RpC1, voB);
            float h00 = fmaf(w0d, pa0.x, w1d * pa0.y);
            float h01 = fmaf(w0d, pb0.x, w1d * pb0.y);
            float h10 = fmaf(w0d, pa1.x, w1d * pa1.y);
            float h11 = fmaf(w0d, pb1.x, w1d * pb1.y);
            float rx = fmaf(dwy0, h00, dwy1 * h01);
            float ry = fmaf(dwy0, h10, dwy1 * h11);
            svh[wv][dyc][dcol] = U32(__floats2half2_rn(rx, ry));
        }
        unsigned lpk;
        {
            F2 pa0 = LOADF2(LpC0, loA);
            F2 pb0 = LOADF2(LpC0, loB);
            F2 pa1 = LOADF2(LpC1, loA);
            F2 pb1 = LOADF2(LpC1, loB);
            float h00 = fmaf(w0l, pa0.x, w1l * pa0.y);
            float h01 = fmaf(w0l, pb0.x, w1l * pb0.y);
            float h10 = fmaf(w0l, pa1.x, w1l * pa1.y);
            float h11 = fmaf(w0l, pb1.x, w1l * pb1.y);
            float lval0 = fmaf(lwy0, h00, lwy1 * h01);
            float lval1 = fmaf(lwy0, h10, lwy1 * h11);
            lpk = U32(__floats2half2_rn(lval0, lval1));
        }

        if (l < DC) {
            __half2 aE = __floats2half2_rn(0.f, 0.f);
            __half2 aO = __floats2half2_rn(0.f, 0.f);
#define TAPROW(YY) {                                                        \
            const unsigned* rp = &svh[wv][YY][DC - 1 - l];                  \
            unsigned q0 = rp[0], q1 = rp[1], q2 = rp[2], q3 = rp[3], q4 = rp[4];\
            unsigned s0 = RDLU(lpk, (YY)*5+0);                              \
            unsigned s1 = RDLU(lpk, (YY)*5+1);                              \
            unsigned s2 = RDLU(lpk, (YY)*5+2);                              \
            unsigned s3 = RDLU(lpk, (YY)*5+3);                              \
            unsigned s4 = RDLU(lpk, (YY)*5+4);                              \
            aE = __hadd2(aE, __habs2(__hsub2(H2(s0), H2(q0))));             \
            aO = __hadd2(aO, __habs2(__hsub2(H2(s1), H2(q1))));             \
            aE = __hadd2(aE, __habs2(__hsub2(H2(s2), H2(q2))));             \
            aO = __hadd2(aO, __habs2(__hsub2(H2(s3), H2(q3))));             \
            aE = __hadd2(aE, __habs2(__hsub2(H2(s4), H2(q4)))); }
            TAPROW(0)
            TAPROW(1)
            TAPROW(2)
            TAPROW(3)
            TAPROW(4)
#undef TAPROW
            __half2 at = __hadd2(aE, aO);
            acc += __half2float(__low2half(at)) + __half2float(__high2half(at));
        }
    }

    if (isP0 && l < 48)
        val4[l] = 1.0f - expf(-acc * (1.0f / 400.0f));

    __syncthreads();                     // the ONLY block-wide barrier

    if (tid < MAXD) {                    // waves 0-2: d == tid
        float v1  = 1.0f - expf(-acc * (1.0f / 400.0f));
        float pos = (float)tid * (47.0f / 191.0f);
        float i0f = floorf(pos);
        int   i0  = (int)i0f;
        float w   = pos - i0f;
        int   i1  = min(i0 + 1, 47);
        float up  = val4[i0] + w * (val4[i1] - val4[i0]);
        out[((size_t)n * MAXD + tid) * 8 + j] = v1 + up;
    }
}

extern "C" void kernel_launch(void* const* d_in, const int* in_sizes, int n_in,
                              void* d_out, int out_size, void* d_ws, size_t ws_size,
                              hipStream_t stream) {
    const float* lf  = (const float*)d_in[0];
    const float* rf  = (const float*)d_in[1];
    const float* pts = (const float*)d_in[2];
    const int*   pW  = (const int*)d_in[3];
    const int*   pH  = (const int*)d_in[4];
    float* out = (float*)d_out;

    const int N = in_sizes[2] / 2;       // (B=1, N, 2)
    pbm_kernel<<<dim3(N, 8), 256, 0, stream>>>(lf, rf, pts, pW, pH, out);
}